// Round 8
// baseline (950.928 us; speedup 1.0000x reference)
//
#include <hip/hip_runtime.h>

// ---------------- problem constants ----------------
#define C_CH   512
#define HFEAT  50
#define WFEAT  50
#define NROIS  256
#define D1     25088   // C_CH * 49
#define H1     4096
#define NHEAD  105     // 21 + 84

typedef __attribute__((ext_vector_type(8))) short short8;
typedef __attribute__((ext_vector_type(4))) float f32x4;

__device__ __forceinline__ unsigned short f2bf(float f) {
  unsigned int u = __float_as_uint(f);
  unsigned int r = (u + 0x7fffu + ((u >> 16) & 1u)) >> 16;
  return (unsigned short)r;
}

// ---------------- feature transpose: [C,H,W] -> [H*W, C] ----------------
__global__ __launch_bounds__(512)
void transpose_feat(const float* __restrict__ feat, float* __restrict__ featT) {
  const int yx = blockIdx.x;        // 0 .. 2499
  const int c  = threadIdx.x;       // 0 .. 511
  featT[(size_t)yx * C_CH + c] = feat[(size_t)c * (HFEAT * WFEAT) + yx];
}

// ---------------- ROI max-pool (adaptive 7x7), fp32 -> bf16 ----------------
__global__ __launch_bounds__(512)
void roi_pool_kernel(const float* __restrict__ featT, const float* __restrict__ boxes,
                     unsigned short* __restrict__ pooled) {
  const int roi = blockIdx.x;
  const int bx1 = (int)(boxes[roi * 4 + 0] * 0.0625f);
  const int by1 = (int)(boxes[roi * 4 + 1] * 0.0625f);
  const int bx2 = (int)(boxes[roi * 4 + 2] * 0.0625f);
  const int by2 = (int)(boxes[roi * 4 + 3] * 0.0625f);

  const int rlo = min(max(by1, 0), HFEAT - 1);
  const int rhi = min(by2, HFEAT - 1);
  const int rn  = max(rhi - rlo + 1, 1);
  const int clo = min(max(bx1, 0), WFEAT - 1);
  const int chi = min(bx2, WFEAT - 1);
  const int cn  = max(chi - clo + 1, 1);

  const int c = threadIdx.x;                      // one channel per thread
  unsigned short* op = pooled + (size_t)roi * D1 + c * 49;

  for (int i = 0; i < 7; ++i) {
    const int r0 = rlo + (i * rn) / 7;
    const int r1 = rlo + ((i + 1) * rn + 6) / 7;
    for (int j = 0; j < 7; ++j) {
      const int c0 = clo + (j * cn) / 7;
      const int c1 = clo + ((j + 1) * cn + 6) / 7;
      float m = -3.402823466e+38f;
      for (int y = r0; y < r1; ++y)
        for (int x = c0; x < c1; ++x)
          m = fmaxf(m, featT[(size_t)(y * WFEAT + x) * C_CH + c]);
      op[i * 7 + j] = f2bf(m);
    }
  }
}

// ---------------- BARRIER-FREE direct-fragment split-K MFMA GEMM ----------------
// A[256,K] bf16 x B[N,K] fp32 -> partials fp32.
// ZERO LDS, ZERO barriers. Both operands are fragment-loaded DIRECTLY from
// global memory with 100% cache-line utilization:
//   A-frag (short8):  64 lanes = 16 rows x 4 k-chunks; per row the 4 kq-lanes
//     cover 64 contiguous bytes = one full 64B line (16 full lines / instr).
//   B-frag (2x float4): per row 128 contiguous bytes = 2 full lines.
// A's z-slice (<=1.6MB) is L2-resident per XCD (z = bid % NZ round-robin);
// B (weights) has zero reuse and streams from HBM exactly once per (z,bn)
// owner block. Each wave free-runs its K-loop with 1-iteration register
// prefetch (loadB(t+1)/loadA(t+1) issued around the MFMAs of t); latency is
// hidden by ILP + independent waves that NEVER rendezvous -- the failure mode
// of all four barrier-structured variants (R4-R7) is structurally removed.
// Block = 256 thr = 4 waves; wave w owns m-rows [64w, 64w+64) x n [bn, bn+64).
template <int NZ, bool TWO_B>
__global__ __launch_bounds__(256)
void gemm_direct(const unsigned short* __restrict__ A,  // [256,K] bf16 bits
                 const float* __restrict__ B,           // [*,K] fp32
                 const float* __restrict__ B2,          // [*,K] fp32 (heads only)
                 float* __restrict__ part,              // [NZ, 256, Nt]
                 const int Nt, const int K,
                 const int kps, const int n_valid) {
  const int bid = (int)blockIdx.x;
  const int z   = bid % NZ;                 // -> XCD pin per dispatch heuristic
  const int bn  = (bid / NZ) * 64;
  const int k0  = z * kps;
  const int nIter = kps >> 5;

  const int tid  = threadIdx.x;
  const int wave = tid >> 6;
  const int lane = tid & 63;
  const int lr   = lane & 15;   // fragment row (m or n)
  const int kq   = lane >> 4;   // k-quad: k = kq*8 .. +7
  const int wm   = wave * 64;   // this wave's m-origin

  // A fragment source: row (wm + im*16 + lr), k-col (k0 + kk + kq*8)
  const unsigned short* asrc = A + (size_t)(wm + lr) * K + k0 + kq * 8;

  // B fragment sources, one per n-frag: row (bn + in*16 + lr)
  const float* bsrc[4];
  bool bval[4];
#pragma unroll
  for (int in = 0; in < 4; ++in) {
    const int n = bn + in * 16 + lr;
    bval[in] = n < n_valid;
    if (TWO_B) {
      if (n < 21)        bsrc[in] = B  + (size_t)n * K;
      else if (bval[in]) bsrc[in] = B2 + (size_t)(n - 21) * K;
      else               bsrc[in] = B;          // valid memory; value zeroed
    } else {
      bsrc[in] = B + (size_t)n * K;
    }
    bsrc[in] += k0 + kq * 8;
  }

  f32x4 acc[4][4];
#pragma unroll
  for (int im = 0; im < 4; ++im)
#pragma unroll
    for (int in = 0; in < 4; ++in)
      acc[im][in] = (f32x4){0.f, 0.f, 0.f, 0.f};

  short8 af[4];          // A fragments for current iter
  float4 st[4][2];       // B fp32 staging for current iter

  auto loadA = [&](int kk) {
#pragma unroll
    for (int im = 0; im < 4; ++im)
      af[im] = *(const short8*)(asrc + (size_t)(im * 16) * K + kk);
  };
  auto loadB = [&](int kk) {
#pragma unroll
    for (int in = 0; in < 4; ++in) {
      st[in][0] = *(const float4*)(bsrc[in] + kk);
      st[in][1] = *(const float4*)(bsrc[in] + kk + 4);
    }
  };

  loadB(0);
  loadA(0);

  for (int it = 0; it < nIter; ++it) {
    const int  kk   = it << 5;
    const bool more = (it + 1) < nIter;

    // convert current B staging -> bf16 fragments (waits only on B(t) loads)
    short8 bf[4];
#pragma unroll
    for (int in = 0; in < 4; ++in) {
      float vv[8] = {st[in][0].x, st[in][0].y, st[in][0].z, st[in][0].w,
                     st[in][1].x, st[in][1].y, st[in][1].z, st[in][1].w};
      if (TWO_B && !bval[in]) {
#pragma unroll
        for (int q = 0; q < 8; ++q) vv[q] = 0.f;
      }
#pragma unroll
      for (int q = 0; q < 8; ++q) bf[in][q] = (short)f2bf(vv[q]);
    }

    if (more) loadB(kk + 32);     // issue next-iter B (HBM stream, 1 iter cover)

    short8 ac[4];
#pragma unroll
    for (int im = 0; im < 4; ++im) ac[im] = af[im];   // consume A(t)

    if (more) loadA(kk + 32);     // issue next-iter A (L2-resident slice)

#pragma unroll
    for (int im = 0; im < 4; ++im)
#pragma unroll
      for (int in = 0; in < 4; ++in)
        acc[im][in] = __builtin_amdgcn_mfma_f32_16x16x32_bf16(ac[im], bf[in], acc[im][in], 0, 0, 0);
  }

  // ---- write fp32 partials: C/D layout col=lane&15 (n), row=kq*4+r (m) ----
#pragma unroll
  for (int im = 0; im < 4; ++im) {
#pragma unroll
    for (int in = 0; in < 4; ++in) {
      const int m0 = wm + im * 16 + kq * 4;
      const int n  = bn + in * 16 + lr;
      float* p = part + ((size_t)z * NROIS + m0) * Nt + n;
#pragma unroll
      for (int r = 0; r < 4; ++r)
        p[(size_t)r * Nt] = acc[im][in][r];
    }
  }
}

// ---------------- split-K reduce + bias + relu + cast to bf16 ----------------
__global__ __launch_bounds__(256)
void reduce_bias_relu(const float* __restrict__ part, const float* __restrict__ bias,
                      unsigned short* __restrict__ out, const int MN, const int nmask,
                      const int S) {
  const int idx = (blockIdx.x * 256 + threadIdx.x) * 4;
  if (idx >= MN) return;
  float4 v = *(const float4*)(part + idx);
  for (int s = 1; s < S; ++s) {
    const float4 p = *(const float4*)(part + (size_t)s * MN + idx);
    v.x += p.x; v.y += p.y; v.z += p.z; v.w += p.w;
  }
  const float4 b = *(const float4*)(bias + (idx & nmask));
  v.x = fmaxf(v.x + b.x, 0.f);
  v.y = fmaxf(v.y + b.y, 0.f);
  v.z = fmaxf(v.z + b.z, 0.f);
  v.w = fmaxf(v.w + b.w, 0.f);
  unsigned long long o = (unsigned long long)f2bf(v.x)
                       | ((unsigned long long)f2bf(v.y) << 16)
                       | ((unsigned long long)f2bf(v.z) << 32)
                       | ((unsigned long long)f2bf(v.w) << 48);
  *(unsigned long long*)(out + idx) = o;
}

// ---------------- heads: reduce + bias, split into class/regr outputs ----------------
__global__ __launch_bounds__(128)
void heads_reduce(const float* __restrict__ part, const float* __restrict__ bc,
                  const float* __restrict__ br, float* __restrict__ out, const int S) {
  const int m = blockIdx.x;
  const int n = threadIdx.x;
  if (n >= NHEAD) return;
  float v = 0.f;
  for (int s = 0; s < S; ++s) v += part[((size_t)s * NROIS + m) * 128 + n];
  if (n < 21) out[m * 21 + n] = v + bc[n];
  else        out[NROIS * 21 + m * 84 + (n - 21)] = v + br[n - 21];
}

// ---------------- launch ----------------
extern "C" void kernel_launch(void* const* d_in, const int* in_sizes, int n_in,
                              void* d_out, int out_size, void* d_ws, size_t ws_size,
                              hipStream_t stream) {
  const float* feat  = (const float*)d_in[0];
  const float* boxes = (const float*)d_in[1];
  const float* W1    = (const float*)d_in[2];
  const float* b1    = (const float*)d_in[3];
  const float* W2    = (const float*)d_in[4];
  const float* b2    = (const float*)d_in[5];
  const float* Wc    = (const float*)d_in[6];
  const float* bc    = (const float*)d_in[7];
  const float* Wr    = (const float*)d_in[8];
  const float* br    = (const float*)d_in[9];
  float* out = (float*)d_out;

  // workspace layout (bytes)
  char* ws = (char*)d_ws;
  unsigned short* pooled = (unsigned short*)(ws);                  // 256*25088*2   = 12,845,056
  float*          part   = (float*)(ws + 12845056);                // 8*256*4096*4  = 33,554,432
  unsigned short* x1     = (unsigned short*)(ws + 46399488);       // 256*4096*2    =  2,097,152
  unsigned short* x2     = (unsigned short*)(ws + 48496640);       // 256*4096*2    =  2,097,152
  float*          hpart  = (float*)(ws + 50593792);                // 16*256*128*4  =  2,097,152
                                                                   // total ~52.7 MB
  // featT [H*W, C] = 5,120,000 B aliases the `part` region: featT is dead
  // before FC1 writes part (same stream, sequential dispatches).
  float*          featT  = part;

  // 1) transpose features for coalesced pooling, then ROI pool -> bf16 [256, 25088]
  transpose_feat<<<HFEAT * WFEAT, 512, 0, stream>>>(feat, featT);
  roi_pool_kernel<<<NROIS, 512, 0, stream>>>(featT, boxes, pooled);

  // 2) FC1: [256,25088] x [4096,25088]^T, splitK=8 (kps=3136), grid 8z x 64bn
  gemm_direct<8, false><<<dim3(512), 256, 0, stream>>>(pooled, W1, W1, part,
      H1, D1, 3136, H1);
  reduce_bias_relu<<<1024, 256, 0, stream>>>(part, b1, x1, NROIS * H1, H1 - 1, 8);

  // 3) FC2: [256,4096] x [4096,4096]^T, splitK=8 (kps=512)
  gemm_direct<8, false><<<dim3(512), 256, 0, stream>>>(x1, W2, W2, part,
      H1, H1, 512, H1);
  reduce_bias_relu<<<1024, 256, 0, stream>>>(part, b2, x2, NROIS * H1, H1 - 1, 8);

  // 4) heads: [256,4096] x [105,4096]^T (N padded to 128), splitK=16 (kps=256)
  //    Wc/Wr fused via per-lane row-pointer select (no concat copy needed).
  gemm_direct<16, true><<<dim3(32), 256, 0, stream>>>(x2, Wc, Wr, hpart,
      128, H1, 256, NHEAD);
  heads_reduce<<<NROIS, 128, 0, stream>>>(hpart, bc, br, out, 16);
}

// Round 9
// 771.215 us; speedup vs baseline: 1.2330x; 1.2330x over previous
//
#include <hip/hip_runtime.h>

// ---------------- problem constants ----------------
#define C_CH   512
#define HFEAT  50
#define WFEAT  50
#define NROIS  256
#define D1     25088   // C_CH * 49
#define H1     4096
#define NHEAD  105     // 21 + 84

typedef __attribute__((ext_vector_type(8))) short short8;
typedef __attribute__((ext_vector_type(4))) float f32x4;

__device__ __forceinline__ unsigned short f2bf(float f) {
  unsigned int u = __float_as_uint(f);
  unsigned int r = (u + 0x7fffu + ((u >> 16) & 1u)) >> 16;
  return (unsigned short)r;
}

// ---------------- feature transpose: [C,H,W] -> [H*W, C] ----------------
__global__ __launch_bounds__(512)
void transpose_feat(const float* __restrict__ feat, float* __restrict__ featT) {
  const int yx = blockIdx.x;        // 0 .. 2499
  const int c  = threadIdx.x;       // 0 .. 511
  featT[(size_t)yx * C_CH + c] = feat[(size_t)c * (HFEAT * WFEAT) + yx];
}

// ---------------- ROI max-pool (adaptive 7x7), fp32 -> bf16 ----------------
__global__ __launch_bounds__(512)
void roi_pool_kernel(const float* __restrict__ featT, const float* __restrict__ boxes,
                     unsigned short* __restrict__ pooled) {
  const int roi = blockIdx.x;
  const int bx1 = (int)(boxes[roi * 4 + 0] * 0.0625f);
  const int by1 = (int)(boxes[roi * 4 + 1] * 0.0625f);
  const int bx2 = (int)(boxes[roi * 4 + 2] * 0.0625f);
  const int by2 = (int)(boxes[roi * 4 + 3] * 0.0625f);

  const int rlo = min(max(by1, 0), HFEAT - 1);
  const int rhi = min(by2, HFEAT - 1);
  const int rn  = max(rhi - rlo + 1, 1);
  const int clo = min(max(bx1, 0), WFEAT - 1);
  const int chi = min(bx2, WFEAT - 1);
  const int cn  = max(chi - clo + 1, 1);

  const int c = threadIdx.x;                      // one channel per thread
  unsigned short* op = pooled + (size_t)roi * D1 + c * 49;

  for (int i = 0; i < 7; ++i) {
    const int r0 = rlo + (i * rn) / 7;
    const int r1 = rlo + ((i + 1) * rn + 6) / 7;
    for (int j = 0; j < 7; ++j) {
      const int c0 = clo + (j * cn) / 7;
      const int c1 = clo + ((j + 1) * cn + 6) / 7;
      float m = -3.402823466e+38f;
      for (int y = r0; y < r1; ++y)
        for (int x = c0; x < c1; ++x)
          m = fmaxf(m, featT[(size_t)(y * WFEAT + x) * C_CH + c]);
      op[i * 7 + j] = f2bf(m);
    }
  }
}

// ---------------- split-K MFMA GEMM: A[256,K] bf16 x B[N,K] fp32 -> partials fp32 ----------------
// BM=256 (whole M), BN=64, BK=64, 256 threads = 4 waves (2m x 2n).
// R9 changes vs the verified-best R4 (797us), mechanism = VMEM txn shape:
//  * B staging FULLY CONTIGUOUS: each round 256thr x 1 float4, 16 thr/row ->
//    every wave-instr covers 4 rows x 256B with zero gaps (16 fully-used 64B
//    lines), replacing the 4thr/row gappy pattern (32 half-used segments).
//  * BK 32->64: halves barrier count (98->49 for FC1); LDS 40KB, still
//    2 blocks/CU (grid-limited, occupancy unchanged).
//  * conflict-free XOR swizzle for 128B rows: 16B-slot s of row r holds
//    k-chunk s^(r&7). A: global_load_lds linear dest + pre-swizzled global
//    source column (rule #21). B: swizzled ds_write byte. Reads: slot =
//    (ks*4+kq)^(lr&7) -> 8 slots x 2 lanes = 2-way (free).
// Each (z,bn) block owns a unique B slice -> B read from HBM exactly once;
// A z-slice L2-resident per XCD via z = bid % NZ.
template <int NZ, bool TWO_B>
__global__ __launch_bounds__(256)
void gemm_bt_splitk(const unsigned short* __restrict__ A,  // [256,K] bf16 bits
                    const float* __restrict__ B,           // [*,K] fp32
                    const float* __restrict__ B2,          // [*,K] fp32 (heads only)
                    float* __restrict__ part,              // [NZ, 256, Nt]
                    const int Nt, const int K,
                    const int kps, const int n_valid) {
  __shared__ __align__(16) unsigned short As[256 * 64];   // 32 KB
  __shared__ __align__(16) unsigned short Bs[64 * 64];    //  8 KB

  const int bid = (int)blockIdx.x;
  const int z   = bid % NZ;                 // -> XCD pin per dispatch heuristic
  const int bn  = (bid / NZ) * 64;
  const int k0  = z * kps;
  const int k1  = k0 + kps;

  const int tid  = threadIdx.x;
  const int wave = tid >> 6;
  const int lane = tid & 63;
  const int lr   = lane & 15;   // fragment row (m or n)
  const int kq   = lane >> 4;   // k-quad within a 32-k substep
  const int wm   = (wave & 1) * 128;
  const int wn   = (wave >> 1) * 32;

  // ---- A staging geometry: 8 gload_lds/wave, each 1KB = 8 rows x 128B ----
  // within a chunk: row = chunk*8 + (lane>>3), 16B-slot s = lane&7;
  // source k-chunk pre-swizzled so LDS slot s of row r holds chunk s^(r&7).
  const int a_rsub = lane >> 3;           // 0..7 row within chunk
  const int a_slot = lane & 7;            // 16B slot in 128B row

  // ---- B staging geometry: 4 rounds, 16 thr/row, contiguous 256B/row ----
  const int b_rsub = tid >> 4;            // 0..15 row within round
  const int b_c    = tid & 15;            // float4 chunk (16B fp32) in row
  const float* bptr[4];
  bool bval[4];
#pragma unroll
  for (int p = 0; p < 4; ++p) {
    const int r = p * 16 + b_rsub;        // row in tile, 0..63
    const int n = bn + r;
    bval[p] = n < n_valid;
    if (TWO_B) {
      if (n < 21)       bptr[p] = B  + (size_t)n * K;
      else if (bval[p]) bptr[p] = B2 + (size_t)(n - 21) * K;
      else              bptr[p] = B;      // valid memory; value zeroed
    } else {
      bptr[p] = B + (size_t)n * K;
    }
    bptr[p] += b_c * 4;
  }

  f32x4 acc[8][2];
#pragma unroll
  for (int im = 0; im < 8; ++im)
#pragma unroll
    for (int in = 0; in < 2; ++in)
      acc[im][in] = (f32x4){0.f, 0.f, 0.f, 0.f};

  for (int kk = k0; kk < k1; kk += 64) {
    __syncthreads();
    // ---- stage A tile (256x64 bf16 = 32KB): 8 gload_lds per wave ----
#pragma unroll
    for (int i = 0; i < 8; ++i) {
      const int chunk = wave * 8 + i;            // 0..31, wave-uniform
      const int row   = chunk * 8 + a_rsub;
      const int scol  = (a_slot ^ (row & 7)) * 8;     // pre-swizzled source
      const unsigned short* g = A + (size_t)row * K + kk + scol;
      __builtin_amdgcn_global_load_lds(
          (const __attribute__((address_space(1))) void*)g,
          (__attribute__((address_space(3))) void*)(As + chunk * 512),
          16, 0, 0);
    }
    // ---- stage B tile (64x64): 4 contiguous rounds, swizzled ds_write ----
#pragma unroll
    for (int p = 0; p < 4; ++p) {
      const int r = p * 16 + b_rsub;
      float4 t = *(const float4*)(bptr[p] + kk);
      if (TWO_B && !bval[p]) t = make_float4(0.f, 0.f, 0.f, 0.f);
      union { unsigned short h[4]; unsigned long long u; } w;
      w.h[0] = f2bf(t.x); w.h[1] = f2bf(t.y); w.h[2] = f2bf(t.z); w.h[3] = f2bf(t.w);
      // fp32 chunk c covers bf16 8B-half (c&1) of 16B k-slot j = c>>1
      const int slot = (b_c >> 1) ^ (r & 7);
      *(unsigned long long*)(Bs + r * 64 + slot * 8 + (b_c & 1) * 4) = w.u;
    }
    __syncthreads();
    // ---- 2 substeps x (10 ds_read_b128 + 16 MFMA) per wave ----
#pragma unroll
    for (int ks = 0; ks < 2; ++ks) {
      const int kc = ks * 4 + kq;                 // k-chunk 0..7
      short8 af[8], bf[2];
#pragma unroll
      for (int im = 0; im < 8; ++im) {
        const int r = wm + im * 16 + lr;
        af[im] = *(const short8*)(As + r * 64 + (kc ^ (r & 7)) * 8);
      }
#pragma unroll
      for (int in = 0; in < 2; ++in) {
        const int r = wn + in * 16 + lr;
        bf[in] = *(const short8*)(Bs + r * 64 + (kc ^ (r & 7)) * 8);
      }
#pragma unroll
      for (int im = 0; im < 8; ++im)
#pragma unroll
        for (int in = 0; in < 2; ++in)
          acc[im][in] = __builtin_amdgcn_mfma_f32_16x16x32_bf16(af[im], bf[in], acc[im][in], 0, 0, 0);
    }
  }

  // ---- write fp32 partials: C/D layout col=lane&15 (n), row=kq*4+r (m) ----
#pragma unroll
  for (int im = 0; im < 8; ++im) {
#pragma unroll
    for (int in = 0; in < 2; ++in) {
      const int m0 = wm + im * 16 + kq * 4;
      const int n  = bn + wn + in * 16 + lr;
      float* p = part + ((size_t)z * NROIS + m0) * Nt + n;
#pragma unroll
      for (int r = 0; r < 4; ++r)
        p[(size_t)r * Nt] = acc[im][in][r];
    }
  }
}

// ---------------- split-K reduce + bias + relu + cast to bf16 ----------------
__global__ __launch_bounds__(256)
void reduce_bias_relu(const float* __restrict__ part, const float* __restrict__ bias,
                      unsigned short* __restrict__ out, const int MN, const int nmask,
                      const int S) {
  const int idx = (blockIdx.x * 256 + threadIdx.x) * 4;
  if (idx >= MN) return;
  float4 v = *(const float4*)(part + idx);
  for (int s = 1; s < S; ++s) {
    const float4 p = *(const float4*)(part + (size_t)s * MN + idx);
    v.x += p.x; v.y += p.y; v.z += p.z; v.w += p.w;
  }
  const float4 b = *(const float4*)(bias + (idx & nmask));
  v.x = fmaxf(v.x + b.x, 0.f);
  v.y = fmaxf(v.y + b.y, 0.f);
  v.z = fmaxf(v.z + b.z, 0.f);
  v.w = fmaxf(v.w + b.w, 0.f);
  unsigned long long o = (unsigned long long)f2bf(v.x)
                       | ((unsigned long long)f2bf(v.y) << 16)
                       | ((unsigned long long)f2bf(v.z) << 32)
                       | ((unsigned long long)f2bf(v.w) << 48);
  *(unsigned long long*)(out + idx) = o;
}

// ---------------- heads: reduce + bias, split into class/regr outputs ----------------
__global__ __launch_bounds__(128)
void heads_reduce(const float* __restrict__ part, const float* __restrict__ bc,
                  const float* __restrict__ br, float* __restrict__ out, const int S) {
  const int m = blockIdx.x;
  const int n = threadIdx.x;
  if (n >= NHEAD) return;
  float v = 0.f;
  for (int s = 0; s < S; ++s) v += part[((size_t)s * NROIS + m) * 128 + n];
  if (n < 21) out[m * 21 + n] = v + bc[n];
  else        out[NROIS * 21 + m * 84 + (n - 21)] = v + br[n - 21];
}

// ---------------- launch ----------------
extern "C" void kernel_launch(void* const* d_in, const int* in_sizes, int n_in,
                              void* d_out, int out_size, void* d_ws, size_t ws_size,
                              hipStream_t stream) {
  const float* feat  = (const float*)d_in[0];
  const float* boxes = (const float*)d_in[1];
  const float* W1    = (const float*)d_in[2];
  const float* b1    = (const float*)d_in[3];
  const float* W2    = (const float*)d_in[4];
  const float* b2    = (const float*)d_in[5];
  const float* Wc    = (const float*)d_in[6];
  const float* bc    = (const float*)d_in[7];
  const float* Wr    = (const float*)d_in[8];
  const float* br    = (const float*)d_in[9];
  float* out = (float*)d_out;

  // workspace layout (bytes)
  char* ws = (char*)d_ws;
  unsigned short* pooled = (unsigned short*)(ws);                  // 256*25088*2   = 12,845,056
  float*          part   = (float*)(ws + 12845056);                // 8*256*4096*4  = 33,554,432
  unsigned short* x1     = (unsigned short*)(ws + 46399488);       // 256*4096*2    =  2,097,152
  unsigned short* x2     = (unsigned short*)(ws + 48496640);       // 256*4096*2    =  2,097,152
  float*          hpart  = (float*)(ws + 50593792);                // 16*256*128*4  =  2,097,152
                                                                   // total ~52.7 MB
  // featT [H*W, C] = 5,120,000 B aliases the `part` region: featT is dead
  // before FC1 writes part (same stream, sequential dispatches).
  float*          featT  = part;

  // 1) transpose features for coalesced pooling, then ROI pool -> bf16 [256, 25088]
  transpose_feat<<<HFEAT * WFEAT, 512, 0, stream>>>(feat, featT);
  roi_pool_kernel<<<NROIS, 512, 0, stream>>>(featT, boxes, pooled);

  // 2) FC1: [256,25088] x [4096,25088]^T, splitK=8 (kps=3136 = 49x64), grid 8z x 64bn
  gemm_bt_splitk<8, false><<<dim3(512), 256, 0, stream>>>(pooled, W1, W1, part,
      H1, D1, 3136, H1);
  reduce_bias_relu<<<1024, 256, 0, stream>>>(part, b1, x1, NROIS * H1, H1 - 1, 8);

  // 3) FC2: [256,4096] x [4096,4096]^T, splitK=8 (kps=512 = 8x64)
  gemm_bt_splitk<8, false><<<dim3(512), 256, 0, stream>>>(x1, W2, W2, part,
      H1, H1, 512, H1);
  reduce_bias_relu<<<1024, 256, 0, stream>>>(part, b2, x2, NROIS * H1, H1 - 1, 8);

  // 4) heads: [256,4096] x [105,4096]^T (N padded to 128), splitK=16 (kps=256 = 4x64)
  //    Wc/Wr fused via per-row pointer select (no concat copy needed).
  gemm_bt_splitk<16, true><<<dim3(32), 256, 0, stream>>>(x2, Wc, Wr, hpart,
      128, H1, 256, NHEAD);
  heads_reduce<<<NROIS, 128, 0, stream>>>(hpart, bc, br, out, 16);
}